// Round 15
// baseline (4236.952 us; speedup 1.0000x reference)
//
#include <hip/hip_runtime.h>

typedef unsigned int u32;
typedef unsigned short u16;
typedef __attribute__((ext_vector_type(2))) _Float16 h2v;
typedef __attribute__((ext_vector_type(4))) _Float16 f16x4;
typedef __attribute__((ext_vector_type(4))) float f32x4;

#define BB 32
#define TT 2048
#define CC 256
#define ESZ 256
#define GG 1024   // 4*es

// W2 per gate-column = 128 h2-rows. Per-thread (4 columns):
//   h2-rows   0..47  -> arch VGPRs (48 x 4 = 192, pin-once; r8/r9 proven)  [MRV]
//   h2-rows  48..111 -> AGPRs (64 x 4 = 256, accvgpr asm; un-remat-able)   [MRA]
//   h2-rows 112..127 -> LDS (4 uint4 chunks x 1024 cols = 65536 B)         [NLC]
#define MRV 48
#define MRA 64
#define NLC 4

// ---------------- helpers ----------------
__device__ __forceinline__ float fdot2u(u32 a, u32 b, float c) {
#if __has_builtin(__builtin_amdgcn_fdot2)
  return __builtin_amdgcn_fdot2(__builtin_bit_cast(h2v, a), __builtin_bit_cast(h2v, b), c, false);
#else
  h2v av = __builtin_bit_cast(h2v, a), bv = __builtin_bit_cast(h2v, b);
  return c + (float)av[0] * (float)bv[0] + (float)av[1] * (float)bv[1];
#endif
}

__device__ __forceinline__ float sigm_f(float x) {
  float e = __builtin_amdgcn_exp2f(x * -1.442695041f);
  return __builtin_amdgcn_rcpf(1.0f + e);
}
__device__ __forceinline__ float tanh_f(float x) {
  float e = __builtin_amdgcn_exp2f(x * 2.885390082f);  // exp(2x)
  return 1.0f - 2.0f * __builtin_amdgcn_rcpf(e + 1.0f);
}

// ---------------- kernel 0: pack W2 (f32 [256][1024] -> h2 rows [128][1024]) ----------------
__global__ void k_pack_w2(const float* __restrict__ W2, u32* __restrict__ W2p) {
  int gid = blockIdx.x * 256 + threadIdx.x;   // m = gid>>10, j = gid&1023
  int m = gid >> 10, j = gid & 1023;
  _Float16 lo = (_Float16)W2[(size_t)(2 * m) * GG + j];
  _Float16 hi = (_Float16)W2[(size_t)(2 * m + 1) * GG + j];
  W2p[gid] = (u32)__builtin_bit_cast(u16, lo) | ((u32)__builtin_bit_cast(u16, hi) << 16);
}

// ---------------- kernel 1: pre = x@W1 + b1 + b2  (f16 MFMA, out f16 [B*T][1024]) ----------------
__global__ __launch_bounds__(256, 2) void k_pre_gemm(
    const float* __restrict__ x, const float* __restrict__ W1,
    const float* __restrict__ b1, const float* __restrict__ b2,
    _Float16* __restrict__ pre) {
  __shared__ __attribute__((aligned(16))) _Float16 Al[128 * 36];
  __shared__ __attribute__((aligned(16))) _Float16 Bl[64 * 36];
  const int tid = threadIdx.x;
  const int lane = tid & 63, wv = tid >> 6;
  const int wr = wv >> 1, wc = wv & 1;
  const int rowBase = blockIdx.x * 128;
  const int colBase = blockIdx.y * 64;

  f32x4 acc[4][2];
#pragma unroll
  for (int mi = 0; mi < 4; ++mi)
#pragma unroll
    for (int ni = 0; ni < 2; ++ni) acc[mi][ni] = (f32x4){0.f, 0.f, 0.f, 0.f};

  for (int k0 = 0; k0 < 256; k0 += 32) {
#pragma unroll
    for (int i = 0; i < 4; ++i) {
      int fidx = tid + 256 * i;
      int row = fidx >> 3, kc = (fidx & 7) * 4;
      const float4 v = *(const float4*)(x + (size_t)(rowBase + row) * 256 + k0 + kc);
      f16x4 hv = { (_Float16)v.x, (_Float16)v.y, (_Float16)v.z, (_Float16)v.w };
      *(f16x4*)&Al[row * 36 + kc] = hv;
    }
#pragma unroll
    for (int i = 0; i < 8; ++i) {
      int idx = tid + 256 * i;
      int k = idx >> 6, n = idx & 63;
      Bl[n * 36 + k] = (_Float16)W1[(size_t)(k0 + k) * GG + colBase + n];
    }
    __syncthreads();

#pragma unroll
    for (int kk = 0; kk < 2; ++kk) {
      int ka = (lane >> 4) * 4 + kk * 16;
      f16x4 af[4], bf[2];
#pragma unroll
      for (int mi = 0; mi < 4; ++mi)
        af[mi] = *(const f16x4*)&Al[(wr * 64 + mi * 16 + (lane & 15)) * 36 + ka];
#pragma unroll
      for (int ni = 0; ni < 2; ++ni)
        bf[ni] = *(const f16x4*)&Bl[(wc * 32 + ni * 16 + (lane & 15)) * 36 + ka];
#pragma unroll
      for (int mi = 0; mi < 4; ++mi)
#pragma unroll
        for (int ni = 0; ni < 2; ++ni)
          acc[mi][ni] = __builtin_amdgcn_mfma_f32_16x16x16f16(af[mi], bf[ni], acc[mi][ni], 0, 0, 0);
    }
    __syncthreads();
  }

#pragma unroll
  for (int ni = 0; ni < 2; ++ni) {
    int col = colBase + wc * 32 + ni * 16 + (lane & 15);
    float bias = b1[col] + b2[col];
#pragma unroll
    for (int mi = 0; mi < 4; ++mi) {
      int r0 = rowBase + wr * 64 + mi * 16 + (lane >> 4) * 4;
#pragma unroll
      for (int rr = 0; rr < 4; ++rr)
        pre[(size_t)(r0 + rr) * GG + col] = (_Float16)(acc[mi][ni][rr] + bias);
    }
  }
}

// ---------------- kernel 2: the recurrence ----------------
// Back to the single-CU r9 skeleton (32 blocks, 256 thr, 1 wave/SIMD, 4 gate
// columns/thread, 1 lgkm-only barrier/step). Multi-CU variants (r10-r14) all
// hit the same ~3.5ms wall = agent-atomic LLC RTT; single-CU has no RTT.
// Change vs r9: h distributed via same-address BROADCAST ds_read_b128 (DS
// pipe, conflict-free) instead of 128 v_readlane (VALU SGPR-hazard chain).
__global__ __launch_bounds__(256, 1)
__attribute__((amdgpu_waves_per_eu(1, 1)))
void k_lstm_rec(
    const _Float16* __restrict__ pre, const u32* __restrict__ W2p,
    const float* __restrict__ h0, const float* __restrict__ c0,
    float* __restrict__ out1, float* __restrict__ out2,
    float* __restrict__ hN, float* __restrict__ cN) {
  extern __shared__ __attribute__((aligned(16))) char smem[];
  uint4* W2Lw = (uint4*)smem;                               // NLC*1024 uint4 = 65536 B
  const uint4* W2L = (const uint4*)smem;
  _Float16* hbuf = (_Float16*)(smem + NLC * 1024 * 16);     // [2][256] f16 = 1024 B

  const int t = threadIdx.x;   // es index 0..255
  const int b = blockIdx.x;

  // ---- arch-VGPR weights: h2-rows 0..MRV-1, cols {t, t+256, t+512, t+768} ----
  u32 wv0[MRV], wv1[MRV], wv2[MRV], wv3[MRV];
#pragma unroll
  for (int m = 0; m < MRV; ++m) {
    wv0[m] = W2p[m * GG + t];
    wv1[m] = W2p[m * GG + t + 256];
    wv2[m] = W2p[m * GG + t + 512];
    wv3[m] = W2p[m * GG + t + 768];
  }
#pragma unroll
  for (int m = 0; m < MRV; ++m)
    asm volatile("" : "+v"(wv0[m]), "+v"(wv1[m]), "+v"(wv2[m]), "+v"(wv3[m]));  // pin ONCE

  // ---- AGPR weights: h2-rows MRV..MRV+MRA-1 (explicit accvgpr_write) ----
  u32 wa0[MRA], wa1[MRA], wa2[MRA], wa3[MRA];
#pragma unroll
  for (int m = 0; m < MRA; ++m) {
    u32 t0 = W2p[(MRV + m) * GG + t];
    u32 t1 = W2p[(MRV + m) * GG + t + 256];
    u32 t2 = W2p[(MRV + m) * GG + t + 512];
    u32 t3 = W2p[(MRV + m) * GG + t + 768];
    asm("v_accvgpr_write_b32 %0, %1" : "=a"(wa0[m]) : "v"(t0));
    asm("v_accvgpr_write_b32 %0, %1" : "=a"(wa1[m]) : "v"(t1));
    asm("v_accvgpr_write_b32 %0, %1" : "=a"(wa2[m]) : "v"(t2));
    asm("v_accvgpr_write_b32 %0, %1" : "=a"(wa3[m]) : "v"(t3));
  }

  // ---- LDS weights: h2-rows MRV+MRA..127, chunk c = rows MRV+MRA+4c..+3 ----
#pragma unroll
  for (int c = 0; c < NLC; ++c) {
    int m0 = MRV + MRA + 4 * c;
#pragma unroll
    for (int g = 0; g < 4; ++g) {
      uint4 v;
      v.x = W2p[(m0 + 0) * GG + t + 256 * g];
      v.y = W2p[(m0 + 1) * GG + t + 256 * g];
      v.z = W2p[(m0 + 2) * GG + t + 256 * g];
      v.w = W2p[(m0 + 3) * GG + t + 256 * g];
      W2Lw[c * 1024 + t + 256 * g] = v;
    }
  }

  float creg = c0[b * ESZ + t];
  hbuf[t] = (_Float16)h0[b * ESZ + t];
  float hlast = 0.f;
  __syncthreads();

  const _Float16* preB = pre + (size_t)b * TT * GG;
  _Float16 q0 = preB[t], q1 = preB[t + 256], q2 = preB[t + 512], q3 = preB[t + 768];

  for (int s = 0; s < TT; ++s) {
    const uint4* hb4 = (const uint4*)(hbuf + (s & 1) * 256);  // h as 32 uint4

    // issue LDS weight chunk 0 early (rolling depth-1 staging, r9-proven)
    uint4 st0 = W2L[t], st1 = W2L[t + 256], st2 = W2L[t + 512], st3 = W2L[t + 768];

    float A0 = (float)q0, A1 = (float)q1, A2 = (float)q2, A3 = (float)q3;
    if (s + 1 < TT) {  // prefetch next step's pre (stays in flight across barrier)
      const _Float16* pn = preB + (size_t)(s + 1) * GG;
      q0 = pn[t]; q1 = pn[t + 256]; q2 = pn[t + 512]; q3 = pn[t + 768];
    }

    // ---- part A: V-rows 0..47, h via broadcast b128 (groups g=0..11) ----
#pragma unroll
    for (int g = 0; g < MRV / 4; ++g) {
      uint4 hh = hb4[g];                     // same addr across wave -> broadcast
      u32 hx[4] = {hh.x, hh.y, hh.z, hh.w};
#pragma unroll
      for (int r = 0; r < 4; ++r) {
        const int m = 4 * g + r;
        A0 = fdot2u(hx[r], wv0[m], A0);
        A1 = fdot2u(hx[r], wv1[m], A1);
        A2 = fdot2u(hx[r], wv2[m], A2);
        A3 = fdot2u(hx[r], wv3[m], A3);
      }
    }

    // ---- parts B+C interleaved: 4 blocks of {4 AGPR groups + 1 LDS chunk} ----
#pragma unroll
    for (int blk = 0; blk < 4; ++blk) {
      // 4 AGPR groups: h groups g = 12 + 4*blk + gi, AGPR idx i0 = 16*blk + 4*gi
#pragma unroll
      for (int gi = 0; gi < 4; ++gi) {
        uint4 hh = hb4[MRV / 4 + 4 * blk + gi];
        u32 hx[4] = {hh.x, hh.y, hh.z, hh.w};
        const int i0 = 16 * blk + 4 * gi;
#pragma unroll
        for (int r = 0; r < 4; ++r) {
          u32 t0, t1, t2, t3;
          asm("v_accvgpr_read_b32 %0, %1" : "=v"(t0) : "a"(wa0[i0 + r]));
          asm("v_accvgpr_read_b32 %0, %1" : "=v"(t1) : "a"(wa1[i0 + r]));
          asm("v_accvgpr_read_b32 %0, %1" : "=v"(t2) : "a"(wa2[i0 + r]));
          asm("v_accvgpr_read_b32 %0, %1" : "=v"(t3) : "a"(wa3[i0 + r]));
          A0 = fdot2u(hx[r], t0, A0);
          A1 = fdot2u(hx[r], t1, A1);
          A2 = fdot2u(hx[r], t2, A2);
          A3 = fdot2u(hx[r], t3, A3);
        }
      }
      // consume LDS weight chunk blk (rows 112+4blk..115+4blk, h group 28+blk)
      {
        uint4 hh = hb4[(MRV + MRA) / 4 + blk];
        u32 hx[4] = {hh.x, hh.y, hh.z, hh.w};
        u32 c0x[4] = {st0.x, st0.y, st0.z, st0.w};
        u32 c1x[4] = {st1.x, st1.y, st1.z, st1.w};
        u32 c2x[4] = {st2.x, st2.y, st2.z, st2.w};
        u32 c3x[4] = {st3.x, st3.y, st3.z, st3.w};
#pragma unroll
        for (int r = 0; r < 4; ++r) {
          A0 = fdot2u(hx[r], c0x[r], A0);
          A1 = fdot2u(hx[r], c1x[r], A1);
          A2 = fdot2u(hx[r], c2x[r], A2);
          A3 = fdot2u(hx[r], c3x[r], A3);
        }
        if (blk < 3) {  // issue next chunk (consumed one AGPR block later)
          st0 = W2L[(blk + 1) * 1024 + t];
          st1 = W2L[(blk + 1) * 1024 + t + 256];
          st2 = W2L[(blk + 1) * 1024 + t + 512];
          st3 = W2L[(blk + 1) * 1024 + t + 768];
        }
      }
    }

    // gates all thread-local: f=A0, i=A1, o=A2, ch=A3
    float fg = sigm_f(A0);
    float ig = sigm_f(A1);
    float og = sigm_f(A2);
    float ch = tanh_f(A3);
    creg = fg * creg + ig * ch;
    float hv = og * tanh_f(creg);
    hlast = hv;

    out1[(size_t)b * TT * ESZ + (size_t)s * ESZ + t] = hv;   // [B, T*es]
    out2[(size_t)s * (BB * ESZ) + b * ESZ + t] = hv;         // [T, B, es]
    hbuf[((s & 1) ^ 1) * 256 + t] = (_Float16)hv;            // next step's h

    // one barrier/step; LDS-only drain (global loads/stores stay in flight)
    asm volatile("s_waitcnt lgkmcnt(0)" ::: "memory");
    __builtin_amdgcn_s_barrier();
  }

  hN[b * ESZ + t] = hlast;
  cN[b * ESZ + t] = creg;
}

// ---------------- launch ----------------
extern "C" void kernel_launch(void* const* d_in, const int* in_sizes, int n_in,
                              void* d_out, int out_size, void* d_ws, size_t ws_size,
                              hipStream_t stream) {
  const float* x  = (const float*)d_in[0];
  const float* h0 = (const float*)d_in[1];
  const float* c0 = (const float*)d_in[2];
  const float* W1 = (const float*)d_in[3];
  const float* W2 = (const float*)d_in[4];
  const float* b1 = (const float*)d_in[5];
  const float* b2 = (const float*)d_in[6];

  float* out1 = (float*)d_out;
  float* out2 = out1 + (size_t)BB * TT * ESZ;
  float* hN   = out2 + (size_t)BB * TT * ESZ;
  float* cN   = hN + BB * ESZ;

  _Float16* pre = (_Float16*)d_ws;                                  // 128 MB
  u32* W2p = (u32*)((char*)d_ws + (size_t)BB * TT * GG * 2);        // 512 KB

  k_pack_w2<<<512, 256, 0, stream>>>(W2, W2p);
  k_pre_gemm<<<dim3(512, 16), 256, 0, stream>>>(x, W1, b1, b2, pre);

  const int ldsBytes = NLC * 1024 * 16 + 1024;  // 65536 W2 + 2x256 f16 h buffers
  hipFuncSetAttribute((const void*)k_lstm_rec, hipFuncAttributeMaxDynamicSharedMemorySize, ldsBytes);
  k_lstm_rec<<<BB, 256, ldsBytes, stream>>>(pre, W2p, h0, c0, out1, out2, hN, cN);
}